// Round 8
// baseline (64.863 us; speedup 1.0000x reference)
//
#include <hip/hip_runtime.h>
#include <math.h>

// Fully fused Preisach hysteresis, single kernel.
// Each block (1024 thr = 16 waves, one per CU) redundantly builds the 2D
// prefix-sum density table in LDS using the round-7-validated spill-free
// scans (wave-per-row, wave-per-column; <=4 floats live state per lane --
// NO register arrays, which is what made rounds 4-6 spill), then its 16
// waves each solve one output t via the exact backward-record scan with
// parallel chunk filter and deferred one-record-per-lane table lookups.
//
// Table: C[a][b] = sum_{alpha_idx<a, beta_idx<b, beta<=alpha} softplus(raw),
// a,b in [0,L], row-major LDS stride SP=W+2=203 (odd -> column-phase lane
// stride coprime with 32 banks). packed p(i,j)=L*i-i(i-1)/2+(j-i).

__device__ __forceinline__ float softplus_f(float x) {
    return fmaxf(x, 0.0f) + log1pf(expf(-fabsf(x)));
}

__global__ __launch_bounds__(1024) void hyst_fused(
    const float* __restrict__ h,
    const float* __restrict__ mesh,
    const float* __restrict__ raw,
    const float* __restrict__ scale,
    const float* __restrict__ offset,
    float* __restrict__ out,
    int T, int L, int n)
{
    extern __shared__ float smem[];
    const int W  = L + 1;            // 201
    const int SP = W + 2;            // 203, odd stride
    const int nc = (T + 63) >> 6;    // 64

    float* S     = smem;             // W * SP floats
    float* umaxs = smem + W * SP;    // nc
    float* dmins = umaxs + nc;       // nc

    const int tid  = threadIdx.x;
    const int lane = tid & 63;
    const int wid  = tid >> 6;
    const int nwv  = blockDim.x >> 6;    // 16

    // ---- per-chunk up-move max / down-move min (wave per chunk) ----
    for (int c = wid; c < nc; c += nwv) {
        const int i = (c << 6) + lane;
        const bool inb = (i < T);
        const float hv = inb ? h[i] : 0.0f;
        const float hp = (inb && i > 0) ? h[i - 1] : 0.0f;
        float mu = (inb && hv > hp) ? hv : -1.0f;
        float md = (inb && hv < hp) ? hv : 2.0f;
        for (int o = 1; o < 64; o <<= 1) {
            mu = fmaxf(mu, __shfl_xor(mu, o));
            md = fminf(md, __shfl_xor(md, o));
        }
        if (lane == 0) { umaxs[c] = mu; dmins[c] = md; }
    }

    // ---- rows: wave per row j (softplus + shfl inclusive scan) ----
    for (int j = wid; j < L; j += nwv) {
        float* row = S + (j + 1) * SP;
        float carry = 0.0f;
        for (int k = 0; 64 * k <= j; ++k) {
            const int i = lane + 64 * k;     // beta index
            float d = 0.0f;
            if (i <= j) {
                const int p = L * i - (i * (i - 1)) / 2 + (j - i);
                d = softplus_f(raw[p]);
            }
            float x = d;
            for (int o = 1; o < 64; o <<= 1) {
                const float tv = __shfl_up(x, o);
                if (lane >= o) x += tv;
            }
            if (i <= j) row[i + 1] = x + carry;
            carry += __shfl(x, 63);
        }
        const float total = carry;
        for (int b = j + 2 + lane; b <= L; b += 64) row[b] = total;
        if (lane == 0) row[0] = 0.0f;
    }
    if (wid == 0) {
        for (int b = lane; b <= L; b += 64) S[b] = 0.0f;  // row a=0
    }
    __syncthreads();

    // ---- cols: wave per column b (shfl scan + carry, registers only) ----
    for (int b = wid; b < W; b += nwv) {
        float carry = 0.0f;
        for (int k = 0; 64 * k < L; ++k) {
            const int a = 1 + lane + 64 * k;
            float x = (a <= L) ? S[a * SP + b] : 0.0f;
            for (int o = 1; o < 64; o <<= 1) {
                const float tv = __shfl_up(x, o);
                if (lane >= o) x += tv;
            }
            if (a <= L) S[a * SP + b] = x + carry;
            carry += __shfl(x, 63);
        }
    }

    // xs levels: lane holds levels lane, +64, +128, +192
    float xsr[4];
#pragma unroll
    for (int k = 0; k < 4; ++k) {
        const int jj = lane + 64 * k;
        xsr[k] = (jj < L) ? mesh[2 * jj + 1] : 2.0f;  // 2.0 never matches
    }
    __syncthreads();

    // ---- main: one wave per t ----
    const int t = blockIdx.x * nwv + wid;
    if (t >= T) return;

    float u_max = -1.0f, d_min = 2.0f;
    int Acov = 0, Bcov = L;
    int nrec = 0;                 // wave-uniform
    int r_up = 0, r_lo = 0, r_Ap = 0, r_Bp = 0;   // per-lane record slot
    float acc = 0.0f;             // per-lane deferred contributions

    auto flushrec = [&]() {
        if (lane < nrec) {
            float contrib;
            if (r_up) {
                contrib = S[r_lo * SP + r_Bp] - S[r_Ap * SP + r_Bp];
            } else {
                contrib = -((S[L * SP + r_Bp] - S[L * SP + r_lo])
                          - (S[r_Ap * SP + r_Bp] - S[r_Ap * SP + r_lo]));
            }
            acc += contrib;
        }
        nrec = 0;
    };
    auto count_le = [&](float v) -> int {
        return __popcll(__ballot(xsr[0] <= v)) + __popcll(__ballot(xsr[1] <= v))
             + __popcll(__ballot(xsr[2] <= v)) + __popcll(__ballot(xsr[3] <= v));
    };
    auto count_lt = [&](float v) -> int {
        return __popcll(__ballot(xsr[0] < v)) + __popcll(__ballot(xsr[1] < v))
             + __popcll(__ballot(xsr[2] < v)) + __popcll(__ballot(xsr[3] < v));
    };
    auto process_chunk = [&](int c) {
        const int i = (c << 6) + lane;
        const int ic = (i < T) ? i : (T - 1);
        const float hv = h[ic];
        const float hp = (ic > 0) ? h[ic - 1] : 0.0f;
        const bool valid = (i <= t);
        const bool isup = valid && (hv > hp);
        const bool isdn = valid && (hv < hp);
        unsigned long long mup = __ballot(isup && hv > u_max);
        unsigned long long mdn = __ballot(isdn && hv < d_min);
        unsigned long long m = mup | mdn;
        while (m) {
            const int rl = 63 - __builtin_clzll(m);   // largest i first
            const float v = __shfl(hv, rl);
            if ((mup >> rl) & 1ull) {
                u_max = v;
                const int lo = count_le(v);
                if (lo > Acov) {
                    if (lane == nrec) { r_up = 1; r_lo = lo; r_Ap = Acov; r_Bp = Bcov; }
                    ++nrec;
                    Acov = lo;
                    if (nrec == 64) flushrec();
                }
            } else {
                d_min = v;
                const int lo = count_lt(v);
                if (lo < Bcov) {
                    if (lane == nrec) { r_up = 0; r_lo = lo; r_Ap = Acov; r_Bp = Bcov; }
                    ++nrec;
                    Bcov = lo;
                    if (nrec == 64) flushrec();
                }
            }
            const unsigned long long below =
                (rl == 0) ? 0ull : ((1ull << rl) - 1ull);
            mup = __ballot(isup && hv > u_max) & below;
            mdn = __ballot(isdn && hv < d_min) & below;
            m = mup | mdn;
        }
    };

    const int ct = t >> 6;
    process_chunk(ct);  // partial top chunk (valid mask), exact

    for (int g = (ct - 1) >> 6; g >= 0; --g) {   // ct==0 -> skipped
        if (Acov >= L || Bcov <= 0) break;
        const int cbase = g << 6;
        const int c = cbase + lane;
        const bool act = (c < ct);
        const float vu = act ? umaxs[c] : -1.0f;
        const float vd = act ? dmins[c] : 2.0f;
        // suffix scans (higher lanes = later chunks in backward order)
        float su = vu, sd = vd;
        for (int o = 1; o < 64; o <<= 1) {
            su = fmaxf(su, __shfl_down(su, o));
            sd = fminf(sd, __shfl_down(sd, o));
        }
        float sue = __shfl_down(su, 1);
        float sde = __shfl_down(sd, 1);
        if (lane == 63) { sue = -1.0f; sde = 2.0f; }
        const bool enter = act && ((vu > fmaxf(u_max, sue)) ||
                                   (vd < fminf(d_min, sde)));
        unsigned long long em = __ballot(enter);
        while (em) {
            const int rl = 63 - __builtin_clzll(em);
            process_chunk(cbase + rl);
            em &= ~(1ull << rl);
            if (Acov >= L || Bcov <= 0) break;
        }
    }

    flushrec();
    // leftover region keeps initial -1
    if (lane == 0) acc -= S[L * SP + Bcov] - S[Acov * SP + Bcov];
    for (int o = 1; o < 64; o <<= 1) acc += __shfl_xor(acc, o);
    if (lane == 0) out[t] = scale[0] * (acc / (float)n) + offset[0];
}

extern "C" void kernel_launch(void* const* d_in, const int* in_sizes, int n_in,
                              void* d_out, int out_size, void* d_ws, size_t ws_size,
                              hipStream_t stream) {
    const float* h      = (const float*)d_in[0];
    const float* mesh   = (const float*)d_in[1];
    const float* raw    = (const float*)d_in[2];
    const float* scale  = (const float*)d_in[3];
    const float* offset = (const float*)d_in[4];
    float* out = (float*)d_out;

    const int T = in_sizes[0];
    const int n = in_sizes[2];
    const int L = (int)((sqrt(8.0 * (double)n + 1.0) - 1.0) / 2.0 + 0.5);
    const int W = L + 1;
    const int SP = W + 2;
    const int nc = (T + 63) / 64;

    const size_t shmem = ((size_t)W * SP + 2 * (size_t)nc) * sizeof(float);
    // 163,724 B <= 163,840 B max group segment on gfx950
    (void)hipFuncSetAttribute(reinterpret_cast<const void*>(hyst_fused),
                              hipFuncAttributeMaxDynamicSharedMemorySize,
                              (int)shmem);

    const int nwv = 16;                       // 1024 threads = 16 waves
    const int grid = (T + nwv - 1) / nwv;     // 256 blocks -> 1/CU
    hipLaunchKernelGGL(hyst_fused, dim3(grid), dim3(1024), shmem, stream,
                       h, mesh, raw, scale, offset, out, T, L, n);
}

// Round 9
// 24.891 us; speedup vs baseline: 2.6058x; 2.6058x over previous
//
#include <hip/hip_runtime.h>
#include <math.h>

// Preisach hysteresis, three small kernels (round-7 structure, which measured
// 26 us; round-8 proved the fused redundant build is VALU-bound and costs
// ~60 us since EVERY CU pays the full build).
// This round: (a) row/col scans use lane->4-contiguous-element mapping so
// each scan is ONE 6-step shfl chain instead of 4 carry-chained ones;
// (b) hyst_main stages h + chunk stats in LDS (block 256 thr, ~17 KB,
// ~8 blocks/CU) cutting entered-chunk latency on the critical wave.
//
// Table: C[a][b] = sum_{alpha_idx<a, beta_idx<b, beta<=alpha} softplus(raw),
// a,b in [0,L], row-major stride SP=202. packed p(i,j)=L*i-i(i-1)/2+(j-i).
// NOTE: single-pass scans assume L+1 <= 256 (here L=200).

__device__ __forceinline__ float softplus_f(float x) {
    return fmaxf(x, 0.0f) + log1pf(expf(-fabsf(x)));
}

__global__ __launch_bounds__(256) void build_rows_stats(
    const float* __restrict__ h,
    const float* __restrict__ raw,
    float* __restrict__ Cg,      // W*SP floats
    float* __restrict__ statg,   // 2*nc floats
    int T, int L, int nrowblocks)
{
    const int W  = L + 1;
    const int SP = (W + 1) & ~1;
    const int nc = (T + 63) >> 6;

    const int lane = threadIdx.x & 63;
    const int wid  = threadIdx.x >> 6;
    const int nwv  = blockDim.x >> 6;   // 4

    if ((int)blockIdx.x < nrowblocks) {
        // ---- row prefix: one wave per row j; lane owns i = 4l..4l+3 ----
        const int j = blockIdx.x * nwv + wid;
        if (j >= L) return;
        float* row = Cg + (size_t)(j + 1) * SP;
        float s[4];
        float run = 0.0f;
#pragma unroll
        for (int q = 0; q < 4; ++q) {
            const int i = 4 * lane + q;          // beta index
            float d = 0.0f;
            if (i <= j) {
                const int p = L * i - (i * (i - 1)) / 2 + (j - i);
                d = softplus_f(raw[p]);
            }
            run += d; s[q] = run;                // lane-local inclusive
        }
        float x = run;                           // lane total
        for (int o = 1; o < 64; o <<= 1) {
            const float tv = __shfl_up(x, o);
            if (lane >= o) x += tv;
        }
        const float excl = x - run;              // exclusive prefix of lanes
#pragma unroll
        for (int q = 0; q < 4; ++q) {
            const int i = 4 * lane + q;
            if (i <= j) row[i + 1] = excl + s[q];
        }
        const float total = __shfl(x, 63);
        for (int b = j + 2 + lane; b <= L; b += 64) row[b] = total;
        if (lane == 0) row[0] = 0.0f;
        if (j == 0) {
            for (int b = lane; b <= L; b += 64) Cg[b] = 0.0f;  // row a=0
        }
    } else {
        // ---- per-chunk up-move max / down-move min ----
        const int c = ((int)blockIdx.x - nrowblocks) * nwv + wid;
        if (c >= nc) return;
        const int i = (c << 6) + lane;
        const bool inb = (i < T);
        const float hv = inb ? h[i] : 0.0f;
        const float hp = (inb && i > 0) ? h[i - 1] : 0.0f;
        float mu = (inb && hv > hp) ? hv : -1.0f;
        float md = (inb && hv < hp) ? hv : 2.0f;
        for (int o = 1; o < 64; o <<= 1) {
            mu = fmaxf(mu, __shfl_xor(mu, o));
            md = fminf(md, __shfl_xor(md, o));
        }
        if (lane == 0) { statg[c] = mu; statg[nc + c] = md; }
    }
}

__global__ __launch_bounds__(256) void build_cols(
    float* __restrict__ Cg, int L)
{
    const int W  = L + 1;
    const int SP = (W + 1) & ~1;
    const int lane = threadIdx.x & 63;
    const int b = blockIdx.x * (blockDim.x >> 6) + (threadIdx.x >> 6);
    if (b >= W) return;

    // lane owns rows a = 1+4l .. 1+4l+3 (contiguous -> one wave scan)
    float v[4];
    float run = 0.0f;
#pragma unroll
    for (int q = 0; q < 4; ++q) {
        const int a = 1 + 4 * lane + q;
        const float d = (a <= L) ? Cg[(size_t)a * SP + b] : 0.0f;
        run += d; v[q] = run;
    }
    float x = run;
    for (int o = 1; o < 64; o <<= 1) {
        const float tv = __shfl_up(x, o);
        if (lane >= o) x += tv;
    }
    const float excl = x - run;
#pragma unroll
    for (int q = 0; q < 4; ++q) {
        const int a = 1 + 4 * lane + q;
        if (a <= L) Cg[(size_t)a * SP + b] = excl + v[q];
    }
}

__global__ __launch_bounds__(256) void hyst_main(
    const float* __restrict__ h,
    const float* __restrict__ mesh,
    const float* __restrict__ Cg,
    const float* __restrict__ statg,
    const float* __restrict__ scale,
    const float* __restrict__ offset,
    float* __restrict__ out,
    int T, int L, int n)
{
    extern __shared__ float sm[];
    const int W  = L + 1;
    const int SP = (W + 1) & ~1;
    const int nc = (T + 63) >> 6;

    float* lh = sm;          // T floats
    float* us = sm + T;      // nc
    float* dsm = us + nc;    // nc

    const int tid  = threadIdx.x;
    const int lane = tid & 63;
    const int wid  = tid >> 6;
    const int nwv  = blockDim.x >> 6;

    // stage h[0..tmax] + chunk stats into LDS
    const int tmax = min(T - 1, (int)(blockIdx.x + 1) * nwv - 1);
    const int nh4  = (tmax + 4) >> 2;           // float4 count covering tmax
    const float4* h4 = (const float4*)h;
    float4* lh4 = (float4*)lh;
    for (int k = tid; k < nh4; k += blockDim.x) lh4[k] = h4[k];
    const int ncb = (tmax >> 6) + 1;
    for (int k = tid; k < ncb; k += blockDim.x) {
        us[k] = statg[k]; dsm[k] = statg[nc + k];
    }

    // xs levels: lane holds levels lane, +64, +128, +192
    float xsr[4];
#pragma unroll
    for (int k = 0; k < 4; ++k) {
        const int jj = lane + 64 * k;
        xsr[k] = (jj < L) ? mesh[2 * jj + 1] : 2.0f;  // 2.0 never matches
    }
    __syncthreads();

    const int t = blockIdx.x * nwv + wid;
    if (t >= T) return;

    float u_max = -1.0f, d_min = 2.0f;
    int Acov = 0, Bcov = L;
    int nrec = 0;                 // wave-uniform
    int r_up = 0, r_lo = 0, r_Ap = 0, r_Bp = 0;   // per-lane record slot
    float acc = 0.0f;             // per-lane deferred contributions

    auto flushrec = [&]() {
        if (lane < nrec) {
            float contrib;
            if (r_up) {
                contrib = Cg[r_lo * SP + r_Bp] - Cg[r_Ap * SP + r_Bp];
            } else {
                contrib = -((Cg[L * SP + r_Bp] - Cg[L * SP + r_lo])
                          - (Cg[r_Ap * SP + r_Bp] - Cg[r_Ap * SP + r_lo]));
            }
            acc += contrib;
        }
        nrec = 0;
    };
    auto count_le = [&](float v) -> int {
        return __popcll(__ballot(xsr[0] <= v)) + __popcll(__ballot(xsr[1] <= v))
             + __popcll(__ballot(xsr[2] <= v)) + __popcll(__ballot(xsr[3] <= v));
    };
    auto count_lt = [&](float v) -> int {
        return __popcll(__ballot(xsr[0] < v)) + __popcll(__ballot(xsr[1] < v))
             + __popcll(__ballot(xsr[2] < v)) + __popcll(__ballot(xsr[3] < v));
    };
    auto process_chunk = [&](int c) {
        const int i = (c << 6) + lane;      // i <= ct*64+63 <= T-1 here
        const float hv = lh[i];
        const float hp = (i > 0) ? lh[i - 1] : 0.0f;
        const bool valid = (i <= t);
        const bool isup = valid && (hv > hp);
        const bool isdn = valid && (hv < hp);
        unsigned long long mup = __ballot(isup && hv > u_max);
        unsigned long long mdn = __ballot(isdn && hv < d_min);
        unsigned long long m = mup | mdn;
        while (m) {
            const int rl = 63 - __builtin_clzll(m);   // largest i first
            const float v = __shfl(hv, rl);
            if ((mup >> rl) & 1ull) {
                u_max = v;
                const int lo = count_le(v);
                if (lo > Acov) {
                    if (lane == nrec) { r_up = 1; r_lo = lo; r_Ap = Acov; r_Bp = Bcov; }
                    ++nrec;
                    Acov = lo;
                    if (nrec == 64) flushrec();
                }
            } else {
                d_min = v;
                const int lo = count_lt(v);
                if (lo < Bcov) {
                    if (lane == nrec) { r_up = 0; r_lo = lo; r_Ap = Acov; r_Bp = Bcov; }
                    ++nrec;
                    Bcov = lo;
                    if (nrec == 64) flushrec();
                }
            }
            const unsigned long long below =
                (rl == 0) ? 0ull : ((1ull << rl) - 1ull);
            mup = __ballot(isup && hv > u_max) & below;
            mdn = __ballot(isdn && hv < d_min) & below;
            m = mup | mdn;
        }
    };

    const int ct = t >> 6;
    process_chunk(ct);  // partial top chunk (valid mask), exact

    for (int g = (ct - 1) >> 6; g >= 0; --g) {   // ct==0 -> skipped
        if (Acov >= L || Bcov <= 0) break;
        const int cbase = g << 6;
        const int c = cbase + lane;
        const bool act = (c < ct);
        const float vu = act ? us[c] : -1.0f;
        const float vd = act ? dsm[c] : 2.0f;
        // suffix scans (higher lanes = later chunks in backward order)
        float su = vu, sd = vd;
        for (int o = 1; o < 64; o <<= 1) {
            su = fmaxf(su, __shfl_down(su, o));
            sd = fminf(sd, __shfl_down(sd, o));
        }
        float sue = __shfl_down(su, 1);
        float sde = __shfl_down(sd, 1);
        if (lane == 63) { sue = -1.0f; sde = 2.0f; }
        const bool enter = act && ((vu > fmaxf(u_max, sue)) ||
                                   (vd < fminf(d_min, sde)));
        unsigned long long em = __ballot(enter);
        while (em) {
            const int rl = 63 - __builtin_clzll(em);
            process_chunk(cbase + rl);
            em &= ~(1ull << rl);
            if (Acov >= L || Bcov <= 0) break;
        }
    }

    flushrec();
    // leftover region keeps initial -1
    if (lane == 0) acc -= Cg[L * SP + Bcov] - Cg[Acov * SP + Bcov];
    for (int o = 1; o < 64; o <<= 1) acc += __shfl_xor(acc, o);
    if (lane == 0) out[t] = scale[0] * (acc / (float)n) + offset[0];
}

extern "C" void kernel_launch(void* const* d_in, const int* in_sizes, int n_in,
                              void* d_out, int out_size, void* d_ws, size_t ws_size,
                              hipStream_t stream) {
    const float* h      = (const float*)d_in[0];
    const float* mesh   = (const float*)d_in[1];
    const float* raw    = (const float*)d_in[2];
    const float* scale  = (const float*)d_in[3];
    const float* offset = (const float*)d_in[4];
    float* out = (float*)d_out;

    const int T = in_sizes[0];
    const int n = in_sizes[2];
    const int L = (int)((sqrt(8.0 * (double)n + 1.0) - 1.0) / 2.0 + 0.5);
    const int W = L + 1;
    const int SP = (W + 1) & ~1;
    const int nc = (T + 63) / 64;

    float* Cg    = (float*)d_ws;              // W*SP floats
    float* statg = Cg + (size_t)W * SP;       // 2*nc floats

    // rows + chunk stats: wave per row / wave per chunk
    const int nrowblocks  = (L + 3) / 4;
    const int nstatblocks = (nc + 3) / 4;
    hipLaunchKernelGGL(build_rows_stats, dim3(nrowblocks + nstatblocks),
                       dim3(256), 0, stream, h, raw, Cg, statg, T, L,
                       nrowblocks);

    // columns: wave per column, single shfl-scan pass
    const int ncolblocks = (W + 3) / 4;
    hipLaunchKernelGGL(build_cols, dim3(ncolblocks), dim3(256), 0, stream,
                       Cg, L);

    // main: wave per t, h + stats staged in LDS
    const int nwv = 4;                         // 256 threads = 4 waves
    const int grid = (T + nwv - 1) / nwv;      // 1024 blocks
    const size_t shmem = (size_t)(T + 2 * nc) * sizeof(float);  // ~16.9 KB
    hipLaunchKernelGGL(hyst_main, dim3(grid), dim3(256), shmem, stream,
                       h, mesh, Cg, statg, scale, offset, out, T, L, n);
}